// Round 20
// baseline (2104.844 us; speedup 1.0000x reference)
//
#include <hip/hip_runtime.h>
#include <math.h>

#define VOCAB  32000
#define EMB    256
#define HID    512
#define MAXLEN 512
#define BATCH  128
#define NCLASS 2

#define NB  16    // blocks = batch groups (8 rows each)
#define RPB 8     // rows per block
#define KP  520   // Wl row stride (bf16 elems)
#define HP  528   // hsb row stride (bf16 elems; 8*HP banks -> 2-way only)
#define WPRIV_ELEMS 65536   // per-block Wpriv: 16 kt x 512 threads x 8 bf16

typedef __attribute__((ext_vector_type(8))) short bf16x8;
typedef __attribute__((ext_vector_type(4))) float f32x4;

// round-to-nearest-even fp32 -> bf16 (bit form)
__device__ __forceinline__ unsigned short f2b_bits(unsigned int u) {
    return (unsigned short)((u + 0x7fffu + ((u >> 16) & 1u)) >> 16);
}

// fast tanh: 1 - 2/(e^{2x}+1) via v_exp_f32 + v_rcp_f32 (~5 VALU ops vs
// ~40 for library tanhf). |err| <~ 1e-6 abs — 3 orders below the bf16
// quantum bounding h. Verified R17: bit-identical absmax, -0.27ms.
__device__ __forceinline__ float fast_tanh(float x) {
    const float t = __builtin_amdgcn_exp2f(x * 2.8853900817779268f); // 2*log2(e)
    return 1.0f - 2.0f * __builtin_amdgcn_rcpf(t + 1.0f);
}

// ---------------------------------------------------------------------------
// Kernel A: embW[v][j] = b_h[j] + sum_e emb[v][e] * W_ih[e][j]  (fp32, exact)
// (unchanged — ~70 us)
// ---------------------------------------------------------------------------
__global__ __launch_bounds__(256, 1) void embw_kernel(
    const float* __restrict__ emb, const float* __restrict__ W_ih,
    const float* __restrict__ b_h, float* __restrict__ embW)
{
    __shared__ __align__(16) float aT[EMB][64];
    __shared__ __align__(16) float wS[32][HID];

    const int t    = threadIdx.x;
    const int row0 = blockIdx.x * 64;

    {
        const int row   = t >> 2;
        const int elane = t & 3;
        for (int i = 0; i < 16; ++i) {
            const int e = elane * 4 + i * 16;
            const float4 v = *reinterpret_cast<const float4*>(
                &emb[(size_t)(row0 + row) * EMB + e]);
            aT[e + 0][row] = v.x;
            aT[e + 1][row] = v.y;
            aT[e + 2][row] = v.z;
            aT[e + 3][row] = v.w;
        }
    }

    const int rg = t >> 5;
    const int cg = t & 31;

    float acc[8][16];
    #pragma unroll
    for (int r = 0; r < 8; ++r)
        #pragma unroll
        for (int c = 0; c < 16; ++c) acc[r][c] = 0.f;

    for (int ec = 0; ec < 8; ++ec) {
        __syncthreads();
        {
            const int j4  = (t & 127) * 4;
            const int keb = (t >> 7);
            #pragma unroll
            for (int i = 0; i < 16; ++i) {
                const int ke = keb + i * 2;
                const float4 v = *reinterpret_cast<const float4*>(
                    &W_ih[(size_t)(ec * 32 + ke) * HID + j4]);
                *reinterpret_cast<float4*>(&wS[ke][j4]) = v;
            }
        }
        __syncthreads();

        for (int ke = 0; ke < 32; ++ke) {
            float a8[8];
            *(float4*)&a8[0] = *(const float4*)&aT[ec * 32 + ke][rg * 8];
            *(float4*)&a8[4] = *(const float4*)&aT[ec * 32 + ke][rg * 8 + 4];
            float w16[16];
            #pragma unroll
            for (int q = 0; q < 4; ++q)
                *(float4*)&w16[q * 4] =
                    *(const float4*)&wS[ke][cg * 16 + q * 4];
            #pragma unroll
            for (int r = 0; r < 8; ++r)
                #pragma unroll
                for (int c = 0; c < 16; ++c)
                    acc[r][c] = fmaf(a8[r], w16[c], acc[r][c]);
        }
    }

    float bh[16];
    #pragma unroll
    for (int q = 0; q < 4; ++q)
        *(float4*)&bh[q * 4] = *(const float4*)&b_h[cg * 16 + q * 4];
    #pragma unroll
    for (int r = 0; r < 8; ++r) {
        const size_t orow = (size_t)(row0 + rg * 8 + r) * HID + cg * 16;
        #pragma unroll
        for (int q = 0; q < 4; ++q) {
            float4 v;
            v.x = acc[r][q * 4 + 0] + bh[q * 4 + 0];
            v.y = acc[r][q * 4 + 1] + bh[q * 4 + 1];
            v.z = acc[r][q * 4 + 2] + bh[q * 4 + 2];
            v.w = acc[r][q * 4 + 3] + bh[q * 4 + 3];
            *reinterpret_cast<float4*>(&embW[orow + q * 4]) = v;
        }
    }
}

// ---------------------------------------------------------------------------
// Kernel B: sequential RNN — EXCHANGE-FREE (R17 structure; R18's ev-prefetch
// REVERTED — it regressed 12%: the same-step gather was already hidden).
// New (USE_GPRIV=1): the 4th W N-tile moves from per-step LDS reads to a
//   per-block L2-resident global panel. R17 accounting: 256 ds_read_b128/
//   CU/step x ~12cy = 1.28us of the 2.07us step; the 128 wrow reads are
//   half. Setup writes Wpriv[bid][kt][t] (128 KB/block, 2 MB total, L2-
//   resident at ~256 KB/XCD); per step 16 coalesced global_load_dwordx4
//   L2-hits replace them — off the LDS pipe, latency covered by the 48
//   register-tile MFMAs. Same-thread same-address write->read separated
//   by __syncthreads (vmcnt drain) — no coherence hazard. Numerics
//   bit-identical (same bf16 values, same MFMA order).
// USE_GPRIV=0 fallback = R17 verbatim (chosen when ws_size is too small).
// 16 blocks x 512 threads; block owns 8 batch rows x ALL 512 cols -> h
// never leaves the CU. W bf16: 48 frags/thread + 1 N-tile via Wpriv/Wl.
// h double-buffered bf16 in hsb. ONE __syncthreads per step. No atomics.
// ---------------------------------------------------------------------------
template <int USE_GPRIV>
__global__ __launch_bounds__(512, 1) void rnn_kernel(
    const int* __restrict__ inputs, const float* __restrict__ embW,
    const float* __restrict__ W_hh, float* __restrict__ h_final,
    unsigned short* __restrict__ Wpriv)
{
    __shared__ __align__(16) unsigned short Wl[128][KP];     // 133,120 B
    __shared__ __align__(16) unsigned short hsb[2][RPB][HP]; //  16,896 B

    const int t  = threadIdx.x;
    const int w  = t >> 6;           // wave 0..7
    const int l  = t & 63;
    const int lm = l & 15;           // MFMA row/col lane index
    const int lk = l >> 4;           // MFMA k-group / D row group
    const int ko = lk * 8;
    const int bid = blockIdx.x;
    const int r0  = bid * RPB;

    // ---- setup: 4 passes stage W cols [p*128, p*128+128) into Wl; the
    //      first 3 -> register frags; the 4th -> Wpriv (or stays in Wl) ----
    bf16x8 Bf[3][16];
    #pragma unroll
    for (int p = 0; p < 4; ++p) {
        if (p > 0) __syncthreads();   // protect Wl against previous readers
        {
            const int c  = t & 127;   // local col
            const int kq = t >> 7;    // k quarter
            for (int i = 0; i < 128; i += 4) {
                const int k = kq * 128 + i;
                unsigned int u0 = __builtin_bit_cast(unsigned int,
                                    W_hh[(size_t)(k + 0) * HID + p * 128 + c]);
                unsigned int u1 = __builtin_bit_cast(unsigned int,
                                    W_hh[(size_t)(k + 1) * HID + p * 128 + c]);
                unsigned int u2 = __builtin_bit_cast(unsigned int,
                                    W_hh[(size_t)(k + 2) * HID + p * 128 + c]);
                unsigned int u3 = __builtin_bit_cast(unsigned int,
                                    W_hh[(size_t)(k + 3) * HID + p * 128 + c]);
                unsigned int p0 = (unsigned int)f2b_bits(u0) |
                                  ((unsigned int)f2b_bits(u1) << 16);
                unsigned int p1 = (unsigned int)f2b_bits(u2) |
                                  ((unsigned int)f2b_bits(u3) << 16);
                *(unsigned long long*)&Wl[c][k] =
                    (unsigned long long)p0 | ((unsigned long long)p1 << 32);
            }
        }
        __syncthreads();
        if (p < 3) {
            #pragma unroll
            for (int kt = 0; kt < 16; ++kt)
                Bf[p][kt] = *(const bf16x8*)&Wl[w * 16 + lm][kt * 32 + ko];
        } else if (USE_GPRIV) {
            // frag-ordered private panel: [kt][t] -> per-instr coalesced
            unsigned short* wpb = Wpriv + (size_t)bid * WPRIV_ELEMS;
            #pragma unroll
            for (int kt = 0; kt < 16; ++kt) {
                const bf16x8 f =
                    *(const bf16x8*)&Wl[w * 16 + lm][kt * 32 + ko];
                *(bf16x8*)&wpb[(kt * 512 + t) * 8] = f;
            }
        }
    }

    // ---- zero h(0) buffer (buffer 0, 8 rows x HP) ----
    for (int i = t; i < RPB * HP / 4; i += 512)
        *(unsigned long long*)&hsb[0][0][i * 4] = 0ull;
    __syncthreads();   // full drain: Wpriv stores complete before any load

    const unsigned short* wpr =
        USE_GPRIV ? (Wpriv + (size_t)bid * WPRIV_ELEMS + (size_t)t * 8)
                  : (const unsigned short*)0;

    int cur = 0;
    for (int ts = 0; ts < MAXLEN; ++ts) {
        // ---- feedforward gather (real rows only: lk<2), issued early;
        //      consumed in epilogue — MFMA phase covers the L3 latency
        //      (R17-proven; R18's deeper prefetch regressed) ----
        float ev[4][4];   // [p][i]
        if (lk < 2) {
            int tok[4];
            #pragma unroll
            for (int i = 0; i < 4; ++i)
                tok[i] = inputs[(r0 + lk * 4 + i) * MAXLEN + ts];
            #pragma unroll
            for (int p = 0; p < 4; ++p)
                #pragma unroll
                for (int i = 0; i < 4; ++i)
                    ev[p][i] = embW[(size_t)tok[i] * HID + p * 128 + w * 16 + lm];
        }

        // ---- MFMA: 16 k-tiles x 4 N-tiles (3 reg + 1 Wpriv/Wl); A shared --
        f32x4 acc0 = {0.f, 0.f, 0.f, 0.f};
        f32x4 acc1 = {0.f, 0.f, 0.f, 0.f};
        f32x4 acc2 = {0.f, 0.f, 0.f, 0.f};
        f32x4 acc3 = {0.f, 0.f, 0.f, 0.f};
        const unsigned short* hrow = &hsb[cur][lm & 7][0];
        const unsigned short* wrow = &Wl[w * 16 + lm][0];
        #pragma unroll
        for (int kt = 0; kt < 16; ++kt) {
            const bf16x8 a = *(const bf16x8*)&hrow[kt * 32 + ko];
            acc0 = __builtin_amdgcn_mfma_f32_16x16x32_bf16(a, Bf[0][kt], acc0, 0, 0, 0);
            acc1 = __builtin_amdgcn_mfma_f32_16x16x32_bf16(a, Bf[1][kt], acc1, 0, 0, 0);
            acc2 = __builtin_amdgcn_mfma_f32_16x16x32_bf16(a, Bf[2][kt], acc2, 0, 0, 0);
            bf16x8 bl;
            if (USE_GPRIV)
                bl = *(const bf16x8*)&wpr[(size_t)kt * 512 * 8];   // L2 hit
            else
                bl = *(const bf16x8*)&wrow[kt * 32 + ko];          // LDS
            acc3 = __builtin_amdgcn_mfma_f32_16x16x32_bf16(a, bl, acc3, 0, 0, 0);
        }

        // ---- fast_tanh + write h back to LDS (real rows lk<2 only) ----
        if (lk < 2) {
            #pragma unroll
            for (int i = 0; i < 4; ++i) {
                const int row = lk * 4 + i;
                const float s0 = fast_tanh(acc0[i] + ev[0][i]);
                const float s1 = fast_tanh(acc1[i] + ev[1][i]);
                const float s2 = fast_tanh(acc2[i] + ev[2][i]);
                const float s3 = fast_tanh(acc3[i] + ev[3][i]);
                hsb[cur ^ 1][row][0 * 128 + w * 16 + lm] =
                    f2b_bits(__builtin_bit_cast(unsigned int, s0));
                hsb[cur ^ 1][row][1 * 128 + w * 16 + lm] =
                    f2b_bits(__builtin_bit_cast(unsigned int, s1));
                hsb[cur ^ 1][row][2 * 128 + w * 16 + lm] =
                    f2b_bits(__builtin_bit_cast(unsigned int, s2));
                hsb[cur ^ 1][row][3 * 128 + w * 16 + lm] =
                    f2b_bits(__builtin_bit_cast(unsigned int, s3));
                if (ts == MAXLEN - 1) {
                    const size_t rowoff = (size_t)(r0 + row) * HID;
                    h_final[rowoff + 0 * 128 + w * 16 + lm] = s0;
                    h_final[rowoff + 1 * 128 + w * 16 + lm] = s1;
                    h_final[rowoff + 2 * 128 + w * 16 + lm] = s2;
                    h_final[rowoff + 3 * 128 + w * 16 + lm] = s3;
                }
            }
        }
        __syncthreads();   // single barrier/step: writes done before reads
        cur ^= 1;
    }
}

// ---------------------------------------------------------------------------
// Kernel C: logits = h_final @ W_out + b_out, sigmoid. Tiny. (fp32 input)
// ---------------------------------------------------------------------------
__global__ void head_kernel(const float* __restrict__ h_final,
                            const float* __restrict__ W_out,
                            const float* __restrict__ b_out,
                            float* __restrict__ out)
{
    const int t = threadIdx.x;
    const int b = t >> 1, c = t & 1;
    float acc = b_out[c];
    for (int k = 0; k < HID; ++k)
        acc = fmaf(h_final[(size_t)b * HID + k], W_out[k * NCLASS + c], acc);
    out[t] = 1.f / (1.f + expf(-acc));
}

// ---------------------------------------------------------------------------
extern "C" void kernel_launch(void* const* d_in, const int* in_sizes, int n_in,
                              void* d_out, int out_size, void* d_ws,
                              size_t ws_size, hipStream_t stream)
{
    const int*   inputs = (const int*)  d_in[0];
    const float* emb    = (const float*)d_in[1];
    const float* W_ih   = (const float*)d_in[2];
    const float* W_hh   = (const float*)d_in[3];
    const float* b_h    = (const float*)d_in[4];
    const float* W_out  = (const float*)d_in[5];
    const float* b_out  = (const float*)d_in[6];
    float* out = (float*)d_out;

    // ws layout: embW 64 MB | h_final 256 KB | Wpriv 2 MB (optional)
    float*          embW    = (float*)d_ws;
    float*          h_final = embW + (size_t)VOCAB * HID;
    unsigned short* Wpriv   = (unsigned short*)(h_final + (size_t)BATCH * HID);

    const size_t needed =
        ((size_t)VOCAB * HID + (size_t)BATCH * HID) * sizeof(float) +
        (size_t)NB * WPRIV_ELEMS * sizeof(unsigned short);

    embw_kernel<<<VOCAB / 64, 256, 0, stream>>>(emb, W_ih, b_h, embW);
    if (ws_size >= needed)
        rnn_kernel<1><<<NB, 512, 0, stream>>>(inputs, embW, W_hh,
                                              h_final, Wpriv);
    else
        rnn_kernel<0><<<NB, 512, 0, stream>>>(inputs, embW, W_hh,
                                              h_final, Wpriv);
    head_kernel<<<1, 256, 0, stream>>>(h_final, W_out, b_out, out);
}

// Round 21
// 1345.713 us; speedup vs baseline: 1.5641x; 1.5641x over previous
//
#include <hip/hip_runtime.h>
#include <math.h>

#define VOCAB  32000
#define EMB    256
#define HID    512
#define MAXLEN 512
#define BATCH  128
#define NCLASS 2

#define NB  16    // blocks = batch groups (8 rows each)
#define RPB 8     // rows per block
#define KP  520   // Wl row stride (bf16 elems)
#define HP  528   // hsb row stride (bf16 elems; 8*HP banks -> 2-way only)

typedef __attribute__((ext_vector_type(8))) short bf16x8;
typedef __attribute__((ext_vector_type(4))) float f32x4;

// round-to-nearest-even fp32 -> bf16 (bit form)
__device__ __forceinline__ unsigned short f2b_bits(unsigned int u) {
    return (unsigned short)((u + 0x7fffu + ((u >> 16) & 1u)) >> 16);
}

// fast tanh: 1 - 2/(e^{2x}+1) via v_exp_f32 + v_rcp_f32. Verified R17:
// bit-identical absmax vs tanhf at bf16 rounding points, -0.27ms.
__device__ __forceinline__ float fast_tanh(float x) {
    const float t = __builtin_amdgcn_exp2f(x * 2.8853900817779268f); // 2*log2(e)
    return 1.0f - 2.0f * __builtin_amdgcn_rcpf(t + 1.0f);
}

// Workgroup barrier that orders LDS only: drains lgkmcnt (ds ops) but NOT
// vmcnt — prefetched read-only global loads stay in flight across steps.
// (R18/R19 lesson: __syncthreads emits s_waitcnt vmcnt(0) before s_barrier,
// which forcibly completes the ev prefetch at the barrier — that drain is
// why source-level prefetch never helped. The loop body's only vmcnt ops
// are read-only gathers + final-step h_final stores (drained at kernel
// end), so skipping the vmcnt drain is safe here.)
__device__ __forceinline__ void lds_barrier() {
    asm volatile("s_waitcnt lgkmcnt(0)\n\ts_barrier" ::: "memory");
}

// ---------------------------------------------------------------------------
// Kernel A: embW[v][j] = b_h[j] + sum_e emb[v][e] * W_ih[e][j]  (fp32, exact)
// (unchanged — ~70 us)
// ---------------------------------------------------------------------------
__global__ __launch_bounds__(256, 1) void embw_kernel(
    const float* __restrict__ emb, const float* __restrict__ W_ih,
    const float* __restrict__ b_h, float* __restrict__ embW)
{
    __shared__ __align__(16) float aT[EMB][64];
    __shared__ __align__(16) float wS[32][HID];

    const int t    = threadIdx.x;
    const int row0 = blockIdx.x * 64;

    {
        const int row   = t >> 2;
        const int elane = t & 3;
        for (int i = 0; i < 16; ++i) {
            const int e = elane * 4 + i * 16;
            const float4 v = *reinterpret_cast<const float4*>(
                &emb[(size_t)(row0 + row) * EMB + e]);
            aT[e + 0][row] = v.x;
            aT[e + 1][row] = v.y;
            aT[e + 2][row] = v.z;
            aT[e + 3][row] = v.w;
        }
    }

    const int rg = t >> 5;
    const int cg = t & 31;

    float acc[8][16];
    #pragma unroll
    for (int r = 0; r < 8; ++r)
        #pragma unroll
        for (int c = 0; c < 16; ++c) acc[r][c] = 0.f;

    for (int ec = 0; ec < 8; ++ec) {
        __syncthreads();
        {
            const int j4  = (t & 127) * 4;
            const int keb = (t >> 7);
            #pragma unroll
            for (int i = 0; i < 16; ++i) {
                const int ke = keb + i * 2;
                const float4 v = *reinterpret_cast<const float4*>(
                    &W_ih[(size_t)(ec * 32 + ke) * HID + j4]);
                *reinterpret_cast<float4*>(&wS[ke][j4]) = v;
            }
        }
        __syncthreads();

        for (int ke = 0; ke < 32; ++ke) {
            float a8[8];
            *(float4*)&a8[0] = *(const float4*)&aT[ec * 32 + ke][rg * 8];
            *(float4*)&a8[4] = *(const float4*)&aT[ec * 32 + ke][rg * 8 + 4];
            float w16[16];
            #pragma unroll
            for (int q = 0; q < 4; ++q)
                *(float4*)&w16[q * 4] =
                    *(const float4*)&wS[ke][cg * 16 + q * 4];
            #pragma unroll
            for (int r = 0; r < 8; ++r)
                #pragma unroll
                for (int c = 0; c < 16; ++c)
                    acc[r][c] = fmaf(a8[r], w16[c], acc[r][c]);
        }
    }

    float bh[16];
    #pragma unroll
    for (int q = 0; q < 4; ++q)
        *(float4*)&bh[q * 4] = *(const float4*)&b_h[cg * 16 + q * 4];
    #pragma unroll
    for (int r = 0; r < 8; ++r) {
        const size_t orow = (size_t)(row0 + rg * 8 + r) * HID + cg * 16;
        #pragma unroll
        for (int q = 0; q < 4; ++q) {
            float4 v;
            v.x = acc[r][q * 4 + 0] + bh[q * 4 + 0];
            v.y = acc[r][q * 4 + 1] + bh[q * 4 + 1];
            v.z = acc[r][q * 4 + 2] + bh[q * 4 + 2];
            v.w = acc[r][q * 4 + 3] + bh[q * 4 + 3];
            *reinterpret_cast<float4*>(&embW[orow + q * 4]) = v;
        }
    }
}

// ---------------------------------------------------------------------------
// Kernel B: sequential RNN — EXCHANGE-FREE (R17 structure, which is the
// proven best at 1.06ms; R19's L2 W-panel REVERTED — L2 latency at 2
// waves/SIMD beat the LDS cost it replaced).
// New vs R17 (one mechanism): in-loop __syncthreads -> lds_barrier()
// (lgkmcnt-only drain) + one-step-ahead ev prefetch. The prefetch is only
// now meaningful: with __syncthreads the compiler's vmcnt(0) drain forced
// prefetched loads to complete AT the barrier (why R18 regressed); with
// the raw barrier they ride across and get a full ~2us step of cover.
// 16 blocks x 512 threads; block owns 8 batch rows x ALL 512 cols -> h
// never leaves the CU. W bf16: 48 frags/thread + 1 N-tile/wave in LDS Wl.
// h double-buffered bf16 in hsb. ONE barrier/step. No atomics.
// ---------------------------------------------------------------------------
__global__ __launch_bounds__(512, 1) void rnn_kernel(
    const int* __restrict__ inputs, const float* __restrict__ embW,
    const float* __restrict__ W_hh, float* __restrict__ h_final)
{
    __shared__ __align__(16) unsigned short Wl[128][KP];     // 133,120 B
    __shared__ __align__(16) unsigned short hsb[2][RPB][HP]; //  16,896 B

    const int t  = threadIdx.x;
    const int w  = t >> 6;           // wave 0..7
    const int l  = t & 63;
    const int lm = l & 15;           // MFMA row/col lane index
    const int lk = l >> 4;           // MFMA k-group / D row group
    const int ko = lk * 8;
    const int r0 = blockIdx.x * RPB;

    // ---- setup: 4 passes stage W cols [p*128, p*128+128) into Wl; the
    //      first 3 are pulled into register frags, the 4th stays in LDS ----
    bf16x8 Bf[3][16];
    #pragma unroll
    for (int p = 0; p < 4; ++p) {
        if (p > 0) __syncthreads();   // protect Wl against previous readers
        {
            const int c  = t & 127;   // local col
            const int kq = t >> 7;    // k quarter
            for (int i = 0; i < 128; i += 4) {
                const int k = kq * 128 + i;
                unsigned int u0 = __builtin_bit_cast(unsigned int,
                                    W_hh[(size_t)(k + 0) * HID + p * 128 + c]);
                unsigned int u1 = __builtin_bit_cast(unsigned int,
                                    W_hh[(size_t)(k + 1) * HID + p * 128 + c]);
                unsigned int u2 = __builtin_bit_cast(unsigned int,
                                    W_hh[(size_t)(k + 2) * HID + p * 128 + c]);
                unsigned int u3 = __builtin_bit_cast(unsigned int,
                                    W_hh[(size_t)(k + 3) * HID + p * 128 + c]);
                unsigned int p0 = (unsigned int)f2b_bits(u0) |
                                  ((unsigned int)f2b_bits(u1) << 16);
                unsigned int p1 = (unsigned int)f2b_bits(u2) |
                                  ((unsigned int)f2b_bits(u3) << 16);
                *(unsigned long long*)&Wl[c][k] =
                    (unsigned long long)p0 | ((unsigned long long)p1 << 32);
            }
        }
        __syncthreads();
        if (p < 3) {
            #pragma unroll
            for (int kt = 0; kt < 16; ++kt)
                Bf[p][kt] = *(const bf16x8*)&Wl[w * 16 + lm][kt * 32 + ko];
        }
    }

    // ---- zero h(0) buffer (buffer 0, 8 rows x HP) ----
    for (int i = t; i < RPB * HP / 4; i += 512)
        *(unsigned long long*)&hsb[0][0][i * 4] = 0ull;
    __syncthreads();

    // ---- prologue: gather ev for ts=0 ----
    float evc[4][4];   // [p][i], valid for lk<2
    if (lk < 2) {
        int tok[4];
        #pragma unroll
        for (int i = 0; i < 4; ++i)
            tok[i] = inputs[(r0 + lk * 4 + i) * MAXLEN + 0];
        #pragma unroll
        for (int p = 0; p < 4; ++p)
            #pragma unroll
            for (int i = 0; i < 4; ++i)
                evc[p][i] = embW[(size_t)tok[i] * HID + p * 128 + w * 16 + lm];
    }

    int cur = 0;
    for (int ts = 0; ts < MAXLEN; ++ts) {
        // ---- prefetch NEXT step's ev (rides across the raw barrier —
        //      a full step of latency cover; tokens static so legal) ----
        float evn[4][4];
        if (lk < 2 && ts + 1 < MAXLEN) {
            int tok[4];
            #pragma unroll
            for (int i = 0; i < 4; ++i)
                tok[i] = inputs[(r0 + lk * 4 + i) * MAXLEN + ts + 1];
            #pragma unroll
            for (int p = 0; p < 4; ++p)
                #pragma unroll
                for (int i = 0; i < 4; ++i)
                    evn[p][i] = embW[(size_t)tok[i] * HID + p * 128 + w * 16 + lm];
        }

        // ---- MFMA: 16 k-tiles x 4 N-tiles (3 reg + 1 LDS); A shared ----
        f32x4 acc0 = {0.f, 0.f, 0.f, 0.f};
        f32x4 acc1 = {0.f, 0.f, 0.f, 0.f};
        f32x4 acc2 = {0.f, 0.f, 0.f, 0.f};
        f32x4 acc3 = {0.f, 0.f, 0.f, 0.f};
        const unsigned short* hrow = &hsb[cur][lm & 7][0];
        const unsigned short* wrow = &Wl[w * 16 + lm][0];
        #pragma unroll
        for (int kt = 0; kt < 16; ++kt) {
            const bf16x8 a = *(const bf16x8*)&hrow[kt * 32 + ko];
            acc0 = __builtin_amdgcn_mfma_f32_16x16x32_bf16(a, Bf[0][kt], acc0, 0, 0, 0);
            acc1 = __builtin_amdgcn_mfma_f32_16x16x32_bf16(a, Bf[1][kt], acc1, 0, 0, 0);
            acc2 = __builtin_amdgcn_mfma_f32_16x16x32_bf16(a, Bf[2][kt], acc2, 0, 0, 0);
            const bf16x8 bl = *(const bf16x8*)&wrow[kt * 32 + ko];
            acc3 = __builtin_amdgcn_mfma_f32_16x16x32_bf16(a, bl, acc3, 0, 0, 0);
        }

        // ---- fast_tanh (uses evc, prefetched last step) + write h ----
        if (lk < 2) {
            #pragma unroll
            for (int i = 0; i < 4; ++i) {
                const int row = lk * 4 + i;
                const float s0 = fast_tanh(acc0[i] + evc[0][i]);
                const float s1 = fast_tanh(acc1[i] + evc[1][i]);
                const float s2 = fast_tanh(acc2[i] + evc[2][i]);
                const float s3 = fast_tanh(acc3[i] + evc[3][i]);
                hsb[cur ^ 1][row][0 * 128 + w * 16 + lm] =
                    f2b_bits(__builtin_bit_cast(unsigned int, s0));
                hsb[cur ^ 1][row][1 * 128 + w * 16 + lm] =
                    f2b_bits(__builtin_bit_cast(unsigned int, s1));
                hsb[cur ^ 1][row][2 * 128 + w * 16 + lm] =
                    f2b_bits(__builtin_bit_cast(unsigned int, s2));
                hsb[cur ^ 1][row][3 * 128 + w * 16 + lm] =
                    f2b_bits(__builtin_bit_cast(unsigned int, s3));
                if (ts == MAXLEN - 1) {
                    const size_t rowoff = (size_t)(r0 + row) * HID;
                    h_final[rowoff + 0 * 128 + w * 16 + lm] = s0;
                    h_final[rowoff + 1 * 128 + w * 16 + lm] = s1;
                    h_final[rowoff + 2 * 128 + w * 16 + lm] = s2;
                    h_final[rowoff + 3 * 128 + w * 16 + lm] = s3;
                }
            }
            // rotate prefetch buffer (dead at ts==MAXLEN-1, unused)
            #pragma unroll
            for (int p = 0; p < 4; ++p)
                #pragma unroll
                for (int i = 0; i < 4; ++i)
                    evc[p][i] = evn[p][i];
        }
        // LDS-only barrier: orders hsb writes/reads, does NOT drain the
        // ev prefetch (the whole point — see lds_barrier comment).
        lds_barrier();
        cur ^= 1;
    }
}

// ---------------------------------------------------------------------------
// Kernel C: logits = h_final @ W_out + b_out, sigmoid. Tiny. (fp32 input)
// ---------------------------------------------------------------------------
__global__ void head_kernel(const float* __restrict__ h_final,
                            const float* __restrict__ W_out,
                            const float* __restrict__ b_out,
                            float* __restrict__ out)
{
    const int t = threadIdx.x;
    const int b = t >> 1, c = t & 1;
    float acc = b_out[c];
    for (int k = 0; k < HID; ++k)
        acc = fmaf(h_final[(size_t)b * HID + k], W_out[k * NCLASS + c], acc);
    out[t] = 1.f / (1.f + expf(-acc));
}

// ---------------------------------------------------------------------------
extern "C" void kernel_launch(void* const* d_in, const int* in_sizes, int n_in,
                              void* d_out, int out_size, void* d_ws,
                              size_t ws_size, hipStream_t stream)
{
    const int*   inputs = (const int*)  d_in[0];
    const float* emb    = (const float*)d_in[1];
    const float* W_ih   = (const float*)d_in[2];
    const float* W_hh   = (const float*)d_in[3];
    const float* b_h    = (const float*)d_in[4];
    const float* W_out  = (const float*)d_in[5];
    const float* b_out  = (const float*)d_in[6];
    float* out = (float*)d_out;

    // ws layout: embW 64 MB | h_final 256 KB
    float* embW    = (float*)d_ws;
    float* h_final = embW + (size_t)VOCAB * HID;

    embw_kernel<<<VOCAB / 64, 256, 0, stream>>>(emb, W_ih, b_h, embW);
    rnn_kernel<<<NB, 512, 0, stream>>>(inputs, embW, W_hh, h_final);
    head_kernel<<<1, 256, 0, stream>>>(h_final, W_out, b_out, out);
}

// Round 22
// 1215.862 us; speedup vs baseline: 1.7312x; 1.1068x over previous
//
#include <hip/hip_runtime.h>
#include <math.h>

#define VOCAB  32000
#define EMB    256
#define HID    512
#define MAXLEN 512
#define BATCH  128
#define NCLASS 2

#define NB  16    // blocks = batch groups (8 rows each)
#define RPB 8     // rows per block
#define KP  520   // Wl row stride (bf16 elems)
#define HP  528   // hsb row stride (bf16 elems; 8*HP banks -> 2-way only)

typedef __attribute__((ext_vector_type(8))) short bf16x8;
typedef __attribute__((ext_vector_type(4))) float f32x4;

// round-to-nearest-even fp32 -> bf16 (bit form)
__device__ __forceinline__ unsigned short f2b_bits(unsigned int u) {
    return (unsigned short)((u + 0x7fffu + ((u >> 16) & 1u)) >> 16);
}

// fast tanh: 1 - 2/(e^{2x}+1) via v_exp_f32 + v_rcp_f32 (~5 VALU ops vs
// ~40 for library tanhf). |err| <~ 1e-6 abs — 3 orders below the bf16
// quantum bounding h. Verified R17: bit-identical absmax, -0.27ms.
__device__ __forceinline__ float fast_tanh(float x) {
    const float t = __builtin_amdgcn_exp2f(x * 2.8853900817779268f); // 2*log2(e)
    return 1.0f - 2.0f * __builtin_amdgcn_rcpf(t + 1.0f);
}

// ---------------------------------------------------------------------------
// Kernel A: embW[v][j] = b_h[j] + sum_e emb[v][e] * W_ih[e][j]  (fp32, exact)
// (unchanged — ~70 us)
// ---------------------------------------------------------------------------
__global__ __launch_bounds__(256, 1) void embw_kernel(
    const float* __restrict__ emb, const float* __restrict__ W_ih,
    const float* __restrict__ b_h, float* __restrict__ embW)
{
    __shared__ __align__(16) float aT[EMB][64];
    __shared__ __align__(16) float wS[32][HID];

    const int t    = threadIdx.x;
    const int row0 = blockIdx.x * 64;

    {
        const int row   = t >> 2;
        const int elane = t & 3;
        for (int i = 0; i < 16; ++i) {
            const int e = elane * 4 + i * 16;
            const float4 v = *reinterpret_cast<const float4*>(
                &emb[(size_t)(row0 + row) * EMB + e]);
            aT[e + 0][row] = v.x;
            aT[e + 1][row] = v.y;
            aT[e + 2][row] = v.z;
            aT[e + 3][row] = v.w;
        }
    }

    const int rg = t >> 5;
    const int cg = t & 31;

    float acc[8][16];
    #pragma unroll
    for (int r = 0; r < 8; ++r)
        #pragma unroll
        for (int c = 0; c < 16; ++c) acc[r][c] = 0.f;

    for (int ec = 0; ec < 8; ++ec) {
        __syncthreads();
        {
            const int j4  = (t & 127) * 4;
            const int keb = (t >> 7);
            #pragma unroll
            for (int i = 0; i < 16; ++i) {
                const int ke = keb + i * 2;
                const float4 v = *reinterpret_cast<const float4*>(
                    &W_ih[(size_t)(ec * 32 + ke) * HID + j4]);
                *reinterpret_cast<float4*>(&wS[ke][j4]) = v;
            }
        }
        __syncthreads();

        for (int ke = 0; ke < 32; ++ke) {
            float a8[8];
            *(float4*)&a8[0] = *(const float4*)&aT[ec * 32 + ke][rg * 8];
            *(float4*)&a8[4] = *(const float4*)&aT[ec * 32 + ke][rg * 8 + 4];
            float w16[16];
            #pragma unroll
            for (int q = 0; q < 4; ++q)
                *(float4*)&w16[q * 4] =
                    *(const float4*)&wS[ke][cg * 16 + q * 4];
            #pragma unroll
            for (int r = 0; r < 8; ++r)
                #pragma unroll
                for (int c = 0; c < 16; ++c)
                    acc[r][c] = fmaf(a8[r], w16[c], acc[r][c]);
        }
    }

    float bh[16];
    #pragma unroll
    for (int q = 0; q < 4; ++q)
        *(float4*)&bh[q * 4] = *(const float4*)&b_h[cg * 16 + q * 4];
    #pragma unroll
    for (int r = 0; r < 8; ++r) {
        const size_t orow = (size_t)(row0 + rg * 8 + r) * HID + cg * 16;
        #pragma unroll
        for (int q = 0; q < 4; ++q) {
            float4 v;
            v.x = acc[r][q * 4 + 0] + bh[q * 4 + 0];
            v.y = acc[r][q * 4 + 1] + bh[q * 4 + 1];
            v.z = acc[r][q * 4 + 2] + bh[q * 4 + 2];
            v.w = acc[r][q * 4 + 3] + bh[q * 4 + 3];
            *reinterpret_cast<float4*>(&embW[orow + q * 4]) = v;
        }
    }
}

// ---------------------------------------------------------------------------
// Kernel B: sequential RNN — EXCHANGE-FREE, session-best R17 VERBATIM.
// (R18/R20 lesson: both ev-prefetch variants — __syncthreads and raw
// lgkmcnt-only barrier — regressed +12-13%: the same-step gather is
// already covered and per-step bookkeeping lands on the serial chain.
// R19 lesson: L2-resident W panel regressed — 16 dependent L2 loads at
// 2 waves/SIMD stall worse than the LDS reads they replace.)
// 16 blocks x 512 threads; block owns 8 batch rows x ALL 512 cols -> h
// never leaves the CU (the R16 insight: batch is embarrassingly parallel;
// no inter-block exchange, no agent atomics, no global h traffic).
// W bf16: 48 frags/thread (3 N-tiles/wave, in unified VGPR/AGPR file,
// forced-materialized by the Wl staging bounce) + 1 N-tile/wave in LDS.
// h double-buffered bf16 in hsb. fast_tanh epilogue. ONE barrier/step.
// Structural floor: 512 serial steps x (256 ds_read_b128/CU/step ~1.28us
// + exposed MFMA/tanh/write chain) ~= 2.07us/step measured.
// ---------------------------------------------------------------------------
__global__ __launch_bounds__(512, 1) void rnn_kernel(
    const int* __restrict__ inputs, const float* __restrict__ embW,
    const float* __restrict__ W_hh, float* __restrict__ h_final)
{
    __shared__ __align__(16) unsigned short Wl[128][KP];     // 133,120 B
    __shared__ __align__(16) unsigned short hsb[2][RPB][HP]; //  16,896 B

    const int t  = threadIdx.x;
    const int w  = t >> 6;           // wave 0..7
    const int l  = t & 63;
    const int lm = l & 15;           // MFMA row/col lane index
    const int lk = l >> 4;           // MFMA k-group / D row group
    const int ko = lk * 8;
    const int r0 = blockIdx.x * RPB;

    // ---- setup: 4 passes stage W cols [p*128, p*128+128) into Wl; the
    //      first 3 are pulled into register frags, the 4th stays in LDS ----
    bf16x8 Bf[3][16];
    #pragma unroll
    for (int p = 0; p < 4; ++p) {
        if (p > 0) __syncthreads();   // protect Wl against previous readers
        {
            const int c  = t & 127;   // local col
            const int kq = t >> 7;    // k quarter
            for (int i = 0; i < 128; i += 4) {
                const int k = kq * 128 + i;
                unsigned int u0 = __builtin_bit_cast(unsigned int,
                                    W_hh[(size_t)(k + 0) * HID + p * 128 + c]);
                unsigned int u1 = __builtin_bit_cast(unsigned int,
                                    W_hh[(size_t)(k + 1) * HID + p * 128 + c]);
                unsigned int u2 = __builtin_bit_cast(unsigned int,
                                    W_hh[(size_t)(k + 2) * HID + p * 128 + c]);
                unsigned int u3 = __builtin_bit_cast(unsigned int,
                                    W_hh[(size_t)(k + 3) * HID + p * 128 + c]);
                unsigned int p0 = (unsigned int)f2b_bits(u0) |
                                  ((unsigned int)f2b_bits(u1) << 16);
                unsigned int p1 = (unsigned int)f2b_bits(u2) |
                                  ((unsigned int)f2b_bits(u3) << 16);
                *(unsigned long long*)&Wl[c][k] =
                    (unsigned long long)p0 | ((unsigned long long)p1 << 32);
            }
        }
        __syncthreads();
        if (p < 3) {
            #pragma unroll
            for (int kt = 0; kt < 16; ++kt)
                Bf[p][kt] = *(const bf16x8*)&Wl[w * 16 + lm][kt * 32 + ko];
        }
    }

    // ---- zero h(0) buffer (buffer 0, 8 rows x HP) ----
    for (int i = t; i < RPB * HP / 4; i += 512)
        *(unsigned long long*)&hsb[0][0][i * 4] = 0ull;
    __syncthreads();

    int cur = 0;
    for (int ts = 0; ts < MAXLEN; ++ts) {
        // ---- feedforward gather (real rows only: lk<2), issued early;
        //      consumed in epilogue — MFMA phase covers the L3 latency ----
        float ev[4][4];   // [p][i]
        if (lk < 2) {
            int tok[4];
            #pragma unroll
            for (int i = 0; i < 4; ++i)
                tok[i] = inputs[(r0 + lk * 4 + i) * MAXLEN + ts];
            #pragma unroll
            for (int p = 0; p < 4; ++p)
                #pragma unroll
                for (int i = 0; i < 4; ++i)
                    ev[p][i] = embW[(size_t)tok[i] * HID + p * 128 + w * 16 + lm];
        }

        // ---- MFMA: 16 k-tiles x 4 N-tiles (3 reg + 1 LDS); A shared ----
        f32x4 acc0 = {0.f, 0.f, 0.f, 0.f};
        f32x4 acc1 = {0.f, 0.f, 0.f, 0.f};
        f32x4 acc2 = {0.f, 0.f, 0.f, 0.f};
        f32x4 acc3 = {0.f, 0.f, 0.f, 0.f};
        const unsigned short* hrow = &hsb[cur][lm & 7][0];
        const unsigned short* wrow = &Wl[w * 16 + lm][0];
        #pragma unroll
        for (int kt = 0; kt < 16; ++kt) {
            const bf16x8 a = *(const bf16x8*)&hrow[kt * 32 + ko];
            acc0 = __builtin_amdgcn_mfma_f32_16x16x32_bf16(a, Bf[0][kt], acc0, 0, 0, 0);
            acc1 = __builtin_amdgcn_mfma_f32_16x16x32_bf16(a, Bf[1][kt], acc1, 0, 0, 0);
            acc2 = __builtin_amdgcn_mfma_f32_16x16x32_bf16(a, Bf[2][kt], acc2, 0, 0, 0);
            const bf16x8 bl = *(const bf16x8*)&wrow[kt * 32 + ko];
            acc3 = __builtin_amdgcn_mfma_f32_16x16x32_bf16(a, bl, acc3, 0, 0, 0);
        }

        // ---- fast_tanh + write h back to LDS (real rows lk<2 only) ----
        if (lk < 2) {
            #pragma unroll
            for (int i = 0; i < 4; ++i) {
                const int row = lk * 4 + i;
                const float s0 = fast_tanh(acc0[i] + ev[0][i]);
                const float s1 = fast_tanh(acc1[i] + ev[1][i]);
                const float s2 = fast_tanh(acc2[i] + ev[2][i]);
                const float s3 = fast_tanh(acc3[i] + ev[3][i]);
                hsb[cur ^ 1][row][0 * 128 + w * 16 + lm] =
                    f2b_bits(__builtin_bit_cast(unsigned int, s0));
                hsb[cur ^ 1][row][1 * 128 + w * 16 + lm] =
                    f2b_bits(__builtin_bit_cast(unsigned int, s1));
                hsb[cur ^ 1][row][2 * 128 + w * 16 + lm] =
                    f2b_bits(__builtin_bit_cast(unsigned int, s2));
                hsb[cur ^ 1][row][3 * 128 + w * 16 + lm] =
                    f2b_bits(__builtin_bit_cast(unsigned int, s3));
                if (ts == MAXLEN - 1) {
                    const size_t rowoff = (size_t)(r0 + row) * HID;
                    h_final[rowoff + 0 * 128 + w * 16 + lm] = s0;
                    h_final[rowoff + 1 * 128 + w * 16 + lm] = s1;
                    h_final[rowoff + 2 * 128 + w * 16 + lm] = s2;
                    h_final[rowoff + 3 * 128 + w * 16 + lm] = s3;
                }
            }
        }
        __syncthreads();   // single barrier/step: writes done before reads
        cur ^= 1;
    }
}

// ---------------------------------------------------------------------------
// Kernel C: logits = h_final @ W_out + b_out, sigmoid. Tiny. (fp32 input)
// ---------------------------------------------------------------------------
__global__ void head_kernel(const float* __restrict__ h_final,
                            const float* __restrict__ W_out,
                            const float* __restrict__ b_out,
                            float* __restrict__ out)
{
    const int t = threadIdx.x;
    const int b = t >> 1, c = t & 1;
    float acc = b_out[c];
    for (int k = 0; k < HID; ++k)
        acc = fmaf(h_final[(size_t)b * HID + k], W_out[k * NCLASS + c], acc);
    out[t] = 1.f / (1.f + expf(-acc));
}

// ---------------------------------------------------------------------------
extern "C" void kernel_launch(void* const* d_in, const int* in_sizes, int n_in,
                              void* d_out, int out_size, void* d_ws,
                              size_t ws_size, hipStream_t stream)
{
    const int*   inputs = (const int*)  d_in[0];
    const float* emb    = (const float*)d_in[1];
    const float* W_ih   = (const float*)d_in[2];
    const float* W_hh   = (const float*)d_in[3];
    const float* b_h    = (const float*)d_in[4];
    const float* W_out  = (const float*)d_in[5];
    const float* b_out  = (const float*)d_in[6];
    float* out = (float*)d_out;

    // ws layout: embW 64 MB | h_final 256 KB
    float* embW    = (float*)d_ws;
    float* h_final = embW + (size_t)VOCAB * HID;

    embw_kernel<<<VOCAB / 64, 256, 0, stream>>>(emb, W_ih, b_h, embW);
    rnn_kernel<<<NB, 512, 0, stream>>>(inputs, embW, W_hh, h_final);
    head_kernel<<<1, 256, 0, stream>>>(h_final, W_out, b_out, out);
}